// Round 7
// baseline (494.660 us; speedup 1.0000x reference)
//
#include <hip/hip_runtime.h>
#include <math.h>

#define NROWS 8192
#define DIM   64
#define KSEL  32
#define NQ    (NROWS - KSEL)   /* 8160 query rows */
#define P1LEN 512              /* pass-1 exact prefix */
#define CAP   1024             /* per-query candidate list capacity */
#define CHUNK 128              /* pass-2 candidate chunk per block */

// ---------------------------------------------------------------------------
// Kernel A: row norms replicating XLA:CPU (LLVM-vectorized fused reduce):
//   VF=8 lanes, init 0, per-lane FMA chain, horizontal shuffle-tree
//   ((r0+r4)+(r2+r6)) + ((r1+r5)+(r3+r7)).   [validated bit-exact R8-R13]
// ---------------------------------------------------------------------------
__global__ void norms_kernel(const float* __restrict__ x, float* __restrict__ sq) {
    int j = blockIdx.x * blockDim.x + threadIdx.x;
    if (j >= NROWS) return;
    const float* xr = x + (size_t)j * DIM;
    float r[8];
#pragma unroll
    for (int u = 0; u < 8; ++u) r[u] = 0.0f;
#pragma unroll
    for (int i = 0; i < DIM; i += 8) {
#pragma unroll
        for (int u = 0; u < 8; ++u)
            r[u] = __fmaf_rn(xr[i + u], xr[i + u], r[u]);
    }
    const float s04 = __fadd_rn(r[0], r[4]);
    const float s26 = __fadd_rn(r[2], r[6]);
    const float s15 = __fadd_rn(r[1], r[5]);
    const float s37 = __fadd_rn(r[3], r[7]);
    sq[j] = __fadd_rn(__fadd_rn(s04, s26), __fadd_rn(s15, s37));
}

// ---------------------------------------------------------------------------
// Pass 1: ONE WAVE per query.  Exact top-32 over prefix [0, min(512, r)):
// 8 keys/lane in registers, 32 shuffle-only extract-min iterations.
// Writes the 32 keys to lists[qi][0..31], cnt[qi]=32, tau0[qi]=32nd key.
// Distance = bit-exact seq-FMA chain k=0..63 (validated).
// ---------------------------------------------------------------------------
__global__ __launch_bounds__(64)
void pass1_kernel(const float* __restrict__ x, const float* __restrict__ sq,
                  unsigned long long* __restrict__ tau0,
                  unsigned int* __restrict__ cnt,
                  unsigned long long* __restrict__ lists) {
    const int qi   = blockIdx.x;        // 0..8159
    const int r    = qi + KSEL;         // query row (wave-uniform)
    const int lane = threadIdx.x;
    const int P    = min(r, P1LEN);

    const float* qp  = x + (size_t)r * DIM;   // uniform -> scalar loads
    const float  sqr = sq[r];

    unsigned long long key[8];
#pragma unroll
    for (int s = 0; s < 8; ++s) {
        const int j = lane + (s << 6);
        unsigned long long k = ~0ull;
        if (j < P) {
            const float4* c4 = reinterpret_cast<const float4*>(x + (size_t)j * DIM);
            float acc = 0.0f;
#pragma unroll
            for (int i = 0; i < DIM / 4; ++i) {
                float4 v = c4[i];
                acc = __fmaf_rn(qp[4 * i + 0], v.x, acc);
                acc = __fmaf_rn(qp[4 * i + 1], v.y, acc);
                acc = __fmaf_rn(qp[4 * i + 2], v.z, acc);
                acc = __fmaf_rn(qp[4 * i + 3], v.w, acc);
            }
            const float dd =
                fmaxf(__fsub_rn(__fadd_rn(sqr, sq[j]), __fmul_rn(2.0f, acc)), 0.0f);
            k = ((unsigned long long)__float_as_uint(dd) << 32) | (unsigned)j;
        }
        key[s] = k;
    }

    unsigned long long pmin = ~0ull;
#pragma unroll
    for (int s = 0; s < 8; ++s) pmin = key[s] < pmin ? key[s] : pmin;

    unsigned long long g = ~0ull;
    for (int it = 0; it < KSEL; ++it) {
        unsigned long long v = pmin;
#pragma unroll
        for (int off = 32; off > 0; off >>= 1) {
            const unsigned long long o = __shfl_down(v, off, 64);
            v = o < v ? o : v;
        }
        g = __shfl(v, 0, 64);
        if (lane == 0) lists[(size_t)qi * CAP + it] = g;
        if (pmin == g) {            // unique winner (keys embed unique j)
#pragma unroll
            for (int s = 0; s < 8; ++s) if (key[s] == g) key[s] = ~0ull;
            pmin = ~0ull;
#pragma unroll
            for (int s = 0; s < 8; ++s) pmin = key[s] < pmin ? key[s] : pmin;
        }
    }
    if (lane == 0) { tau0[qi] = g; cnt[qi] = KSEL; }
}

// ---------------------------------------------------------------------------
// Pass 2 (v6): REGISTER-RESIDENT-Q, wave-uniform-candidate filter.
// POST-MORTEM LADDER: all LDS-staged variants (v1 4x4=165us, v2 8x8/64KB=
// 304us, v3/v4 8x8 spilled=277/243us, v5 4x8=202us) idle ~80% of cycles
// (VALUBusy 19-24%, conflicts negligible) -> LATENCY-bound on
// ds_read->FMA at ~2 waves/SIMD, re-exposed by per-tile barriers.  v6
// removes the memory pipe from the inner loop instead of optimizing it:
//   * ONE WAVE per block, ONE QUERY PER LANE: q row (64 floats) in VGPRs,
//     loaded once per block (L2-hot).
//   * Candidates iterated WAVE-UNIFORMLY, 4 at a time: c-row addresses are
//     uniform -> s_load_dwordx4 (SGPR operand; v_fma takes 1 SGPR src) or
//     all-lanes-same-addr L1 broadcast.  NO LDS, NO barriers.
//   * Inner loop = 4 FMAs per uniform 16-B load, ILP 4 (4 indep chains).
//   * Epilogue atomics hit per-lane-DISTINCT cnt[qi] (no same-addr
//     serialization within the wave).
//   * __launch_bounds__(64, 1): do NOT let the allocator cap below the
//     ~85-100 live set (v3/v4 lesson) -> no spill, ~5 waves/SIMD.
// Chains run k=0..63 ascending == validated bit-exact Eigen chain.
// Accept rule unchanged: bits(dist) <= tau_hi (superset), atomicAdd.
// ---------------------------------------------------------------------------
__global__ __launch_bounds__(64, 1)
void pass2_kernel(const float* __restrict__ x, const float* __restrict__ sq,
                  const unsigned long long* __restrict__ tau0,
                  unsigned int* __restrict__ cnt,
                  unsigned long long* __restrict__ lists) {
    const int qb   = blockIdx.x;                        // 0..127 (64 q/block)
    const int jb   = P1LEN + blockIdx.y * CHUNK;        // candidate chunk base
    const int r_hi = min(qb * 64 + 96, NROWS);          // max query row + 1
    if (jb >= r_hi) return;                             // uniform exit

    const int lane = threadIdx.x;
    const int qi   = qb * 64 + lane;                    // may be >= NQ (tail)
    const int r    = qi + KSEL;                         // query row
    const int rq   = min(r, NROWS - 1);
    const bool valid = (qi < NQ);

    // ---- q row -> 64 VGPRs (per-lane distinct row, L2-hot, once per block)
    float qr[DIM];
    {
        const float4* qp4 = reinterpret_cast<const float4*>(x + (size_t)rq * DIM);
#pragma unroll
        for (int i = 0; i < DIM / 4; ++i) {
            const float4 v = qp4[i];
            qr[4 * i + 0] = v.x; qr[4 * i + 1] = v.y;
            qr[4 * i + 2] = v.z; qr[4 * i + 3] = v.w;
        }
    }
    const float    sqr = sq[rq];
    const unsigned th  = valid ? (unsigned)(tau0[qi] >> 32) : 0u;

    const int jend = min(jb + CHUNK, r_hi);             // always multiple of 4

    for (int j0 = jb; j0 < jend; j0 += 4) {
        const float* cr0 = x + (size_t)(j0 + 0) * DIM;  // wave-uniform rows
        const float* cr1 = x + (size_t)(j0 + 1) * DIM;
        const float* cr2 = x + (size_t)(j0 + 2) * DIM;
        const float* cr3 = x + (size_t)(j0 + 3) * DIM;
        float a0 = 0.f, a1 = 0.f, a2 = 0.f, a3 = 0.f;
#pragma unroll
        for (int k = 0; k < DIM; k += 4) {
            const float4 v0 = *reinterpret_cast<const float4*>(cr0 + k);
            const float4 v1 = *reinterpret_cast<const float4*>(cr1 + k);
            const float4 v2 = *reinterpret_cast<const float4*>(cr2 + k);
            const float4 v3 = *reinterpret_cast<const float4*>(cr3 + k);
            a0 = __fmaf_rn(qr[k + 0], v0.x, a0);
            a1 = __fmaf_rn(qr[k + 0], v1.x, a1);
            a2 = __fmaf_rn(qr[k + 0], v2.x, a2);
            a3 = __fmaf_rn(qr[k + 0], v3.x, a3);
            a0 = __fmaf_rn(qr[k + 1], v0.y, a0);
            a1 = __fmaf_rn(qr[k + 1], v1.y, a1);
            a2 = __fmaf_rn(qr[k + 1], v2.y, a2);
            a3 = __fmaf_rn(qr[k + 1], v3.y, a3);
            a0 = __fmaf_rn(qr[k + 2], v0.z, a0);
            a1 = __fmaf_rn(qr[k + 2], v1.z, a1);
            a2 = __fmaf_rn(qr[k + 2], v2.z, a2);
            a3 = __fmaf_rn(qr[k + 2], v3.z, a3);
            a0 = __fmaf_rn(qr[k + 3], v0.w, a0);
            a1 = __fmaf_rn(qr[k + 3], v1.w, a1);
            a2 = __fmaf_rn(qr[k + 3], v2.w, a2);
            a3 = __fmaf_rn(qr[k + 3], v3.w, a3);
        }
#pragma unroll
        for (int i = 0; i < 4; ++i) {
            const int   j  = j0 + i;
            const float av = (i == 0) ? a0 : (i == 1) ? a1 : (i == 2) ? a2 : a3;
            const float dd = fmaxf(
                __fsub_rn(__fadd_rn(sqr, sq[j]), __fmul_rn(2.0f, av)), 0.0f);
            const unsigned bits = __float_as_uint(dd);
            if (valid && j < r && bits <= th) {
                const unsigned s = atomicAdd(&cnt[qi], 1u);
                if (s < CAP)
                    lists[(size_t)qi * CAP + s] =
                        ((unsigned long long)bits << 32) | (unsigned)j;
            }
        }
    }
}

// ---------------------------------------------------------------------------
// Merge: ONE WAVE per query.  16 keys/lane in registers, 32 shuffle-only
// extract-min iterations.  u64-min = ascending (dist, index), low-index
// ties (validated top_k semantics).  List is a superset of the true top-32.
// ---------------------------------------------------------------------------
__global__ __launch_bounds__(64)
void merge_kernel(const unsigned long long* __restrict__ lists,
                  const unsigned int* __restrict__ cnt,
                  float* __restrict__ out_d, float* __restrict__ out_i) {
    const int qi   = blockIdx.x;     // 0..8159
    const int lane = threadIdx.x;
    const int ne   = min((int)cnt[qi], CAP);
    const unsigned long long* src = lists + (size_t)qi * CAP;

    unsigned long long k[16];
#pragma unroll
    for (int s = 0; s < 16; ++s) {
        const int idx = lane + (s << 6);
        k[s] = (idx < ne) ? src[idx] : ~0ull;
    }
    unsigned long long pmin = ~0ull;
#pragma unroll
    for (int s = 0; s < 16; ++s) pmin = k[s] < pmin ? k[s] : pmin;

    for (int it = 0; it < KSEL; ++it) {
        unsigned long long v = pmin;
#pragma unroll
        for (int off = 32; off > 0; off >>= 1) {
            const unsigned long long o = __shfl_down(v, off, 64);
            v = o < v ? o : v;
        }
        const unsigned long long g = __shfl(v, 0, 64);
        if (lane == 0) {
            out_d[(size_t)qi * KSEL + it] = __uint_as_float((unsigned)(g >> 32));
            out_i[(size_t)qi * KSEL + it] = (float)(unsigned)(g & 0xFFFFFFFFu);
        }
        if (pmin == g) {            // unique winner rescans its registers
#pragma unroll
            for (int s = 0; s < 16; ++s) if (k[s] == g) k[s] = ~0ull;
            pmin = ~0ull;
#pragma unroll
            for (int s = 0; s < 16; ++s) pmin = k[s] < pmin ? k[s] : pmin;
        }
    }
}

extern "C" void kernel_launch(void* const* d_in, const int* in_sizes, int n_in,
                              void* d_out, int out_size, void* d_ws, size_t ws_size,
                              hipStream_t stream) {
    const float* x = (const float*)d_in[0];    // anchor_x [8192, 64] fp32
    float* sq = (float*)d_ws;                                        // 32 KB
    unsigned long long* tau0 =
        (unsigned long long*)((char*)d_ws + 32768);                  // 64 KB
    unsigned int* cnt = (unsigned int*)((char*)d_ws + 98304);        // 32 KB
    unsigned long long* lists =
        (unsigned long long*)((char*)d_ws + 131072);                 // 66.8 MB
    float* out_d = (float*)d_out;              // [8160, 32] distances
    float* out_i = out_d + (size_t)NQ * KSEL;  // [8160, 32] indices (as fp32)

    norms_kernel<<<NROWS / 256, 256, 0, stream>>>(x, sq);
    pass1_kernel<<<NQ, 64, 0, stream>>>(x, sq, tau0, cnt, lists);
    dim3 g2(128, (NROWS - P1LEN) / CHUNK);     // (query block, candidate chunk)
    pass2_kernel<<<g2, 64, 0, stream>>>(x, sq, tau0, cnt, lists);
    merge_kernel<<<NQ, 64, 0, stream>>>(lists, cnt, out_d, out_i);
}